// Round 8
// baseline (464.270 us; speedup 1.0000x reference)
//
#include <hip/hip_runtime.h>
#include <math.h>

#define NE 8
#define HD 2048
#define ID 1408
#define NT 512
#define FP8MAX 448.0f

typedef __attribute__((ext_vector_type(4))) float floatx4;

__device__ __forceinline__ floatx4 fzero4() {
    floatx4 z; z.x = 0.f; z.y = 0.f; z.z = 0.f; z.w = 0.f; return z;
}

// ---- ws layout (bytes) ----
#define OFF_OFFS  0                         // int[16]
#define OFF_TOK   1024                      // int[1024]
#define OFF_WGT   8192                      // float[1024]
#define OFF_ENT   16384                     // int[1024]  (slot -> entry)
#define OFF_XSG   32768                     // float[1024*16] entry-ordered x scales
#define OFF_XG    131072                    // u8[1024*2048] entry-ordered x codes (2 MB)
#define OFF_HS    (3*1024*1024)             // float[1024*11]
#define OFF_HQ    (3*1024*1024 + 65536)     // u8[1024*1408]
#define OFF_GU0   (5*1024*1024)             // float[1024*2816] K-half-0 partials (11.5 MB)
#define OFF_GU1   (17*1024*1024)            // float[1024*2816] K-half-1 partials

// ---------------- routing ----------------
__global__ void route_kernel(const int* __restrict__ tki,
                             const float* __restrict__ tkw,
                             int* __restrict__ offs,
                             int* __restrict__ tok,
                             float* __restrict__ wgt,
                             int* __restrict__ ent) {
    __shared__ int cnt[NE];
    __shared__ int cur[NE];
    __shared__ int base[NE + 1];
    int tid = threadIdx.x;               // 1024 threads, one per (token, slot)
    if (tid < NE) { cnt[tid] = 0; cur[tid] = 0; }
    __syncthreads();
    int e = tki[tid];
    atomicAdd(&cnt[e], 1);
    __syncthreads();
    if (tid == 0) {
        int s = 0;
        for (int i = 0; i < NE; i++) { base[i] = s; s += cnt[i]; }
        base[NE] = s;
    }
    __syncthreads();
    int pos = atomicAdd(&cur[e], 1);
    int j = base[e] + pos;
    tok[j] = tid >> 1;                   // token id
    wgt[j] = tkw[tid];
    ent[tid] = j;                        // inverse map: (token,slot) -> entry
    if (tid <= NE) offs[tid] = base[tid];
}

// ---------------- x quantization + entry-ordered scatter ---------------------
__global__ void quant_x_kernel(const float* __restrict__ x,
                               const int* __restrict__ ent,
                               unsigned char* __restrict__ xg,
                               float* __restrict__ xsg) {
    int wid = (blockIdx.x * 256 + threadIdx.x) >> 6;   // 0..8191
    int lane = threadIdx.x & 63;
    int t = wid >> 4;
    int b = wid & 15;
    const float2 v = *(const float2*)(x + (long)t * HD + b * 128 + lane * 2);
    float am = fmaxf(fabsf(v.x), fabsf(v.y));
    #pragma unroll
    for (int m = 32; m; m >>= 1) am = fmaxf(am, __shfl_xor(am, m));
    float scale = fmaxf(am, 1e-12f) / FP8MAX;
    int p = __builtin_amdgcn_cvt_pk_fp8_f32(v.x / scale, v.y / scale, 0, false);
    unsigned short pk = (unsigned short)(p & 0xffff);
    int e0 = ent[2 * t], e1 = ent[2 * t + 1];
    *(unsigned short*)(xg + (long)e0 * HD + b * 128 + lane * 2) = pk;
    *(unsigned short*)(xg + (long)e1 * HD + b * 128 + lane * 2) = pk;
    if (lane == 0) { xsg[e0 * 16 + b] = scale; xsg[e1 * 16 + b] = scale; }
}

// ---------------- h: sum K-halves, silu*up, quantize -------------------------
__global__ void quant_h_kernel(const float* __restrict__ gu0,
                               const float* __restrict__ gu1,
                               unsigned char* __restrict__ hq,
                               float* __restrict__ hs) {
    int wid = (blockIdx.x * 256 + threadIdx.x) >> 6;   // 0..11263
    int lane = threadIdx.x & 63;
    int j = wid / 11;
    int b = wid - j * 11;
    long base = (long)j * 2816 + b * 128 + lane * 2;
    float2 ga = *(const float2*)(gu0 + base);
    float2 gb = *(const float2*)(gu1 + base);
    float2 ua = *(const float2*)(gu0 + base + 1408);
    float2 ub = *(const float2*)(gu1 + base + 1408);
    float gx = ga.x + gb.x, gy = ga.y + gb.y;
    float ux = ua.x + ub.x, uy = ua.y + ub.y;
    float hx = (gx / (1.0f + expf(-gx))) * ux;
    float hy = (gy / (1.0f + expf(-gy))) * uy;
    float am = fmaxf(fabsf(hx), fabsf(hy));
    #pragma unroll
    for (int m = 32; m; m >>= 1) am = fmaxf(am, __shfl_xor(am, m));
    float scale = fmaxf(am, 1e-12f) / FP8MAX;
    int p = __builtin_amdgcn_cvt_pk_fp8_f32(hx / scale, hy / scale, 0, false);
    *(unsigned short*)(hq + (long)j * ID + b * 128 + lane * 2) =
        (unsigned short)(p & 0xffff);
    if (lane == 0) hs[j * 11 + b] = scale;
}

// ---------------- gemm1: barrier-free, fragment-direct loads -----------------
// Per wave: BM=64 entries x (16 gate + 16 up) cols; K-half split across blocks.
// No LDS for A/B: each lane loads its MFMA fragment bytes straight from global
// (A: 8B from entry-ordered xg; B: 2x float4 fp32 -> cvt_pk_fp8 in-register).
__global__ __launch_bounds__(256, 3) void gemm1_kernel(
    const unsigned char* __restrict__ xg,
    const float* __restrict__ xsg,
    const float* __restrict__ wgu,   // [E][2816][2048] fp32 codes
    const float* __restrict__ sgu,   // [E][22][16]
    const int* __restrict__ offs,
    float* __restrict__ gu0,
    float* __restrict__ gu1) {
    int e = blockIdx.z;
    int mt = blockIdx.y;
    int jb = blockIdx.x >> 1;        // 0..21 (64-col tile; each wave owns 16)
    int kh = blockIdx.x & 1;         // K half
    int o0 = offs[e], o1 = offs[e + 1];
    int ne = o1 - o0;
    int m0 = mt * 64;
    if (m0 >= ne) return;
    int rem = ne - m0;
    int j0 = o0 + m0;

    __shared__ __align__(16) float sxa[16][64];  // [kb][row] x scales, staged once
    int tid = threadIdx.x;
    {
        int r = tid & 63, kq = tid >> 6;
        int j = j0 + r; if (j >= o1) j = o0;
        float4 s = *(const float4*)(xsg + j * 16 + kq * 4);
        sxa[kq * 4 + 0][r] = s.x; sxa[kq * 4 + 1][r] = s.y;
        sxa[kq * 4 + 2][r] = s.z; sxa[kq * 4 + 3][r] = s.w;
    }
    __syncthreads();                 // the only barrier

    int wave = tid >> 6;
    int lane = tid & 63;
    int l15 = lane & 15;
    int quad = lane >> 4;
    int c0 = jb * 64 + wave * 16;    // this wave's gate-col tile base

    const unsigned char *aP0, *aP1, *aP2, *aP3;
    {
        int j;
        j = j0 + l15;      if (j >= o1) j = o0; aP0 = xg + (long)j * HD + quad * 8;
        j = j0 + 16 + l15; if (j >= o1) j = o0; aP1 = xg + (long)j * HD + quad * 8;
        j = j0 + 32 + l15; if (j >= o1) j = o0; aP2 = xg + (long)j * HD + quad * 8;
        j = j0 + 48 + l15; if (j >= o1) j = o0; aP3 = xg + (long)j * HD + quad * 8;
    }
    const float* bg = wgu + ((long)e * 2816 + c0 + l15) * HD + quad * 8;
    const float* bu = wgu + ((long)e * 2816 + 1408 + c0 + l15) * HD + quad * 8;
    const float* sgp = sgu + (e * 22 + (c0 >> 7)) * 16;
    const float* sup = sgu + (e * 22 + 11 + (c0 >> 7)) * 16;

    floatx4 facc[8];                 // [mi][gate/up]
    #pragma unroll
    for (int i = 0; i < 8; i++) facc[i] = fzero4();

    for (int kb = kh * 8; kb < kh * 8 + 8; kb++) {
        floatx4 cacc[8];
        #pragma unroll
        for (int i = 0; i < 8; i++) cacc[i] = fzero4();
        #pragma unroll
        for (int ks = 0; ks < 4; ks++) {
            int ko = kb * 128 + ks * 32;
            long a0 = *(const long*)(aP0 + ko);
            long a1 = *(const long*)(aP1 + ko);
            long a2 = *(const long*)(aP2 + ko);
            long a3 = *(const long*)(aP3 + ko);
            float4 g0 = *(const float4*)(bg + ko);
            float4 g1 = *(const float4*)(bg + ko + 4);
            float4 u0 = *(const float4*)(bu + ko);
            float4 u1 = *(const float4*)(bu + ko + 4);
            int pl = __builtin_amdgcn_cvt_pk_fp8_f32(g0.x, g0.y, 0, false);
            pl = __builtin_amdgcn_cvt_pk_fp8_f32(g0.z, g0.w, pl, true);
            int ph = __builtin_amdgcn_cvt_pk_fp8_f32(g1.x, g1.y, 0, false);
            ph = __builtin_amdgcn_cvt_pk_fp8_f32(g1.z, g1.w, ph, true);
            long bgv = (long)(unsigned)pl | ((long)ph << 32);
            pl = __builtin_amdgcn_cvt_pk_fp8_f32(u0.x, u0.y, 0, false);
            pl = __builtin_amdgcn_cvt_pk_fp8_f32(u0.z, u0.w, pl, true);
            ph = __builtin_amdgcn_cvt_pk_fp8_f32(u1.x, u1.y, 0, false);
            ph = __builtin_amdgcn_cvt_pk_fp8_f32(u1.z, u1.w, ph, true);
            long buv = (long)(unsigned)pl | ((long)ph << 32);
            cacc[0] = __builtin_amdgcn_mfma_f32_16x16x32_fp8_fp8(a0, bgv, cacc[0], 0, 0, 0);
            cacc[1] = __builtin_amdgcn_mfma_f32_16x16x32_fp8_fp8(a0, buv, cacc[1], 0, 0, 0);
            cacc[2] = __builtin_amdgcn_mfma_f32_16x16x32_fp8_fp8(a1, bgv, cacc[2], 0, 0, 0);
            cacc[3] = __builtin_amdgcn_mfma_f32_16x16x32_fp8_fp8(a1, buv, cacc[3], 0, 0, 0);
            cacc[4] = __builtin_amdgcn_mfma_f32_16x16x32_fp8_fp8(a2, bgv, cacc[4], 0, 0, 0);
            cacc[5] = __builtin_amdgcn_mfma_f32_16x16x32_fp8_fp8(a2, buv, cacc[5], 0, 0, 0);
            cacc[6] = __builtin_amdgcn_mfma_f32_16x16x32_fp8_fp8(a3, bgv, cacc[6], 0, 0, 0);
            cacc[7] = __builtin_amdgcn_mfma_f32_16x16x32_fp8_fp8(a3, buv, cacc[7], 0, 0, 0);
        }
        float sg = sgp[kb];
        float su = sup[kb];
        #pragma unroll
        for (int mi = 0; mi < 4; mi++) {
            floatx4 sxv = *(const floatx4*)&sxa[kb][mi * 16 + quad * 4];
            #pragma unroll
            for (int reg = 0; reg < 4; reg++) {
                facc[mi * 2 + 0][reg] += cacc[mi * 2 + 0][reg] * (sxv[reg] * sg);
                facc[mi * 2 + 1][reg] += cacc[mi * 2 + 1][reg] * (sxv[reg] * su);
            }
        }
    }

    float* gu = kh ? gu1 : gu0;
    #pragma unroll
    for (int mi = 0; mi < 4; mi++) {
        #pragma unroll
        for (int reg = 0; reg < 4; reg++) {
            int r = mi * 16 + quad * 4 + reg;
            if (r < rem) {
                long base = (long)(j0 + r) * 2816;
                gu[base + c0 + l15] = facc[mi * 2 + 0][reg];
                gu[base + 1408 + c0 + l15] = facc[mi * 2 + 1][reg];
            }
        }
    }
}

// ---------------- gemm2: barrier-free, weighted atomic scatter ---------------
__global__ __launch_bounds__(256, 4) void gemm2_kernel(
    const unsigned char* __restrict__ hq,
    const float* __restrict__ hs,
    const float* __restrict__ wd,    // [E][2048][1408] fp32 codes
    const float* __restrict__ sd,    // [E][16][11]
    const int* __restrict__ offs,
    const int* __restrict__ tok,
    const float* __restrict__ wgt,
    float* __restrict__ out) {
    int e = blockIdx.z;
    int mt = blockIdx.y;
    int jb = blockIdx.x >> 1;        // 0..31 (64 H-cols; each wave owns 16)
    int kh = blockIdx.x & 1;
    int o0 = offs[e], o1 = offs[e + 1];
    int ne = o1 - o0;
    int m0 = mt * 64;
    if (m0 >= ne) return;
    int rem = ne - m0;
    int j0 = o0 + m0;

    __shared__ __align__(16) float sha[11][64];
    __shared__ int tokL[64];
    __shared__ float wgtL[64];
    int tid = threadIdx.x;
    if (tid < 64) {
        int j = j0 + tid;
        int valid = j < o1;
        if (!valid) j = o0;
        tokL[tid] = tok[j];
        wgtL[tid] = valid ? wgt[j] : 0.0f;
        #pragma unroll
        for (int k = 0; k < 11; k++) sha[k][tid] = hs[j * 11 + k];
    }
    __syncthreads();                 // the only barrier

    int wave = tid >> 6;
    int lane = tid & 63;
    int l15 = lane & 15;
    int quad = lane >> 4;
    int c0 = jb * 64 + wave * 16;

    const unsigned char *aP0, *aP1, *aP2, *aP3;
    {
        int j;
        j = j0 + l15;      if (j >= o1) j = o0; aP0 = hq + (long)j * ID + quad * 8;
        j = j0 + 16 + l15; if (j >= o1) j = o0; aP1 = hq + (long)j * ID + quad * 8;
        j = j0 + 32 + l15; if (j >= o1) j = o0; aP2 = hq + (long)j * ID + quad * 8;
        j = j0 + 48 + l15; if (j >= o1) j = o0; aP3 = hq + (long)j * ID + quad * 8;
    }
    const float* bp = wd + ((long)e * 2048 + c0 + l15) * ID + quad * 8;
    const float* sdp = sd + (e * 16 + (c0 >> 7)) * 11;

    floatx4 facc[4];
    #pragma unroll
    for (int i = 0; i < 4; i++) facc[i] = fzero4();

    int kb0 = kh ? 6 : 0, kb1 = kh ? 11 : 6;
    for (int kb = kb0; kb < kb1; kb++) {
        floatx4 cacc[4];
        #pragma unroll
        for (int i = 0; i < 4; i++) cacc[i] = fzero4();
        #pragma unroll
        for (int ks = 0; ks < 4; ks++) {
            int ko = kb * 128 + ks * 32;
            long a0 = *(const long*)(aP0 + ko);
            long a1 = *(const long*)(aP1 + ko);
            long a2 = *(const long*)(aP2 + ko);
            long a3 = *(const long*)(aP3 + ko);
            float4 f0 = *(const float4*)(bp + ko);
            float4 f1 = *(const float4*)(bp + ko + 4);
            int pl = __builtin_amdgcn_cvt_pk_fp8_f32(f0.x, f0.y, 0, false);
            pl = __builtin_amdgcn_cvt_pk_fp8_f32(f0.z, f0.w, pl, true);
            int ph = __builtin_amdgcn_cvt_pk_fp8_f32(f1.x, f1.y, 0, false);
            ph = __builtin_amdgcn_cvt_pk_fp8_f32(f1.z, f1.w, ph, true);
            long bv = (long)(unsigned)pl | ((long)ph << 32);
            cacc[0] = __builtin_amdgcn_mfma_f32_16x16x32_fp8_fp8(a0, bv, cacc[0], 0, 0, 0);
            cacc[1] = __builtin_amdgcn_mfma_f32_16x16x32_fp8_fp8(a1, bv, cacc[1], 0, 0, 0);
            cacc[2] = __builtin_amdgcn_mfma_f32_16x16x32_fp8_fp8(a2, bv, cacc[2], 0, 0, 0);
            cacc[3] = __builtin_amdgcn_mfma_f32_16x16x32_fp8_fp8(a3, bv, cacc[3], 0, 0, 0);
        }
        float sw = sdp[kb];
        #pragma unroll
        for (int mi = 0; mi < 4; mi++) {
            floatx4 shv = *(const floatx4*)&sha[kb][mi * 16 + quad * 4];
            #pragma unroll
            for (int reg = 0; reg < 4; reg++)
                facc[mi][reg] += cacc[mi][reg] * (shv[reg] * sw);
        }
    }

    #pragma unroll
    for (int mi = 0; mi < 4; mi++) {
        #pragma unroll
        for (int reg = 0; reg < 4; reg++) {
            int r = mi * 16 + quad * 4 + reg;
            if (r < rem) {
                float v = facc[mi][reg] * wgtL[r];
                atomicAdd(out + (long)tokL[r] * HD + c0 + l15, v);
            }
        }
    }
}

extern "C" void kernel_launch(void* const* d_in, const int* in_sizes, int n_in,
                              void* d_out, int out_size, void* d_ws, size_t ws_size,
                              hipStream_t stream) {
    (void)in_sizes; (void)n_in; (void)out_size; (void)ws_size;
    const float* x   = (const float*)d_in[0];
    const int*   tki = (const int*)d_in[1];
    const float* tkw = (const float*)d_in[2];
    const float* wgu = (const float*)d_in[3];
    const float* sgu = (const float*)d_in[4];
    const float* wd  = (const float*)d_in[5];
    const float* sd  = (const float*)d_in[6];
    float* out = (float*)d_out;
    char* ws = (char*)d_ws;

    int*   offs = (int*)(ws + OFF_OFFS);
    int*   tok  = (int*)(ws + OFF_TOK);
    float* wgt  = (float*)(ws + OFF_WGT);
    int*   ent  = (int*)(ws + OFF_ENT);
    float* xsg  = (float*)(ws + OFF_XSG);
    unsigned char* xg = (unsigned char*)(ws + OFF_XG);
    float* hs   = (float*)(ws + OFF_HS);
    unsigned char* hq = (unsigned char*)(ws + OFF_HQ);
    float* gu0  = (float*)(ws + OFF_GU0);
    float* gu1  = (float*)(ws + OFF_GU1);

    hipMemsetAsync(d_out, 0, (size_t)NT * HD * sizeof(float), stream);
    route_kernel<<<1, 1024, 0, stream>>>(tki, tkw, offs, tok, wgt, ent);
    quant_x_kernel<<<2048, 256, 0, stream>>>(x, ent, xg, xsg);
    gemm1_kernel<<<dim3(44, 16, NE), 256, 0, stream>>>(xg, xsg, wgu, sgu, offs, gu0, gu1);
    quant_h_kernel<<<2816, 256, 0, stream>>>(gu0, gu1, hq, hs);
    gemm2_kernel<<<dim3(64, 16, NE), 256, 0, stream>>>(hq, hs, wd, sd, offs, tok, wgt, out);
}

// Round 9
// 362.710 us; speedup vs baseline: 1.2800x; 1.2800x over previous
//
#include <hip/hip_runtime.h>
#include <math.h>

#define NE 8
#define HD 2048
#define ID 1408
#define NT 512
#define FP8MAX 448.0f

typedef __attribute__((ext_vector_type(4))) float floatx4;

__device__ __forceinline__ floatx4 fzero4() {
    floatx4 z; z.x = 0.f; z.y = 0.f; z.z = 0.f; z.w = 0.f; return z;
}

// ---- ws layout (bytes) ----
#define OFF_OFFS  0                         // int[16]
#define OFF_TOK   1024                      // int[1024]
#define OFF_WGT   8192                      // float[1024]
#define OFF_ENT   16384                     // int[1024]  (slot -> entry)
#define OFF_XSG   32768                     // float[1024*16] entry-ordered x scales
#define OFF_XG    131072                    // u8[1024*2048] entry-ordered x codes (2 MB)
#define OFF_HS    (3*1024*1024)             // float[1024*11]
#define OFF_HQ    (3*1024*1024 + 65536)     // u8[1024*1408]
#define OFF_GU0   (5*1024*1024)             // float[1024*2816] K-half-0 partials (11.5 MB)
#define OFF_GU1   (17*1024*1024)            // float[1024*2816] K-half-1 partials

#define LDA 136   // LDS row pitch for 128-byte fp8 rows

// ---------------- routing ----------------
__global__ void route_kernel(const int* __restrict__ tki,
                             const float* __restrict__ tkw,
                             int* __restrict__ offs,
                             int* __restrict__ tok,
                             float* __restrict__ wgt,
                             int* __restrict__ ent) {
    __shared__ int cnt[NE];
    __shared__ int cur[NE];
    __shared__ int base[NE + 1];
    int tid = threadIdx.x;               // 1024 threads, one per (token, slot)
    if (tid < NE) { cnt[tid] = 0; cur[tid] = 0; }
    __syncthreads();
    int e = tki[tid];
    atomicAdd(&cnt[e], 1);
    __syncthreads();
    if (tid == 0) {
        int s = 0;
        for (int i = 0; i < NE; i++) { base[i] = s; s += cnt[i]; }
        base[NE] = s;
    }
    __syncthreads();
    int pos = atomicAdd(&cur[e], 1);
    int j = base[e] + pos;
    tok[j] = tid >> 1;                   // token id
    wgt[j] = tkw[tid];
    ent[tid] = j;                        // inverse map: (token,slot) -> entry
    if (tid <= NE) offs[tid] = base[tid];
}

// ---------------- x quantization + entry-ordered scatter ---------------------
__global__ void quant_x_kernel(const float* __restrict__ x,
                               const int* __restrict__ ent,
                               unsigned char* __restrict__ xg,
                               float* __restrict__ xsg) {
    int wid = (blockIdx.x * 256 + threadIdx.x) >> 6;   // 0..8191
    int lane = threadIdx.x & 63;
    int t = wid >> 4;
    int b = wid & 15;
    const float2 v = *(const float2*)(x + (long)t * HD + b * 128 + lane * 2);
    float am = fmaxf(fabsf(v.x), fabsf(v.y));
    #pragma unroll
    for (int m = 32; m; m >>= 1) am = fmaxf(am, __shfl_xor(am, m));
    float scale = fmaxf(am, 1e-12f) / FP8MAX;
    int p = __builtin_amdgcn_cvt_pk_fp8_f32(v.x / scale, v.y / scale, 0, false);
    unsigned short pk = (unsigned short)(p & 0xffff);
    int e0 = ent[2 * t], e1 = ent[2 * t + 1];
    *(unsigned short*)(xg + (long)e0 * HD + b * 128 + lane * 2) = pk;
    *(unsigned short*)(xg + (long)e1 * HD + b * 128 + lane * 2) = pk;
    if (lane == 0) { xsg[e0 * 16 + b] = scale; xsg[e1 * 16 + b] = scale; }
}

// ---------------- h: sum K-halves, silu*up, quantize -------------------------
__global__ void quant_h_kernel(const float* __restrict__ gu0,
                               const float* __restrict__ gu1,
                               unsigned char* __restrict__ hq,
                               float* __restrict__ hs) {
    int wid = (blockIdx.x * 256 + threadIdx.x) >> 6;   // 0..11263
    int lane = threadIdx.x & 63;
    int j = wid / 11;
    int b = wid - j * 11;
    long base = (long)j * 2816 + b * 128 + lane * 2;
    float2 ga = *(const float2*)(gu0 + base);
    float2 gb = *(const float2*)(gu1 + base);
    float2 ua = *(const float2*)(gu0 + base + 1408);
    float2 ub = *(const float2*)(gu1 + base + 1408);
    float gx = ga.x + gb.x, gy = ga.y + gb.y;
    float ux = ua.x + ub.x, uy = ua.y + ub.y;
    float hx = (gx / (1.0f + expf(-gx))) * ux;
    float hy = (gy / (1.0f + expf(-gy))) * uy;
    float am = fmaxf(fabsf(hx), fabsf(hy));
    #pragma unroll
    for (int m = 32; m; m >>= 1) am = fmaxf(am, __shfl_xor(am, m));
    float scale = fmaxf(am, 1e-12f) / FP8MAX;
    int p = __builtin_amdgcn_cvt_pk_fp8_f32(hx / scale, hy / scale, 0, false);
    *(unsigned short*)(hq + (long)j * ID + b * 128 + lane * 2) =
        (unsigned short)(p & 0xffff);
    if (lane == 0) hs[j * 11 + b] = scale;
}

// ---------------- gemm1: BM=128 x 32 gate/up col pairs, K-split-2 ------------
// r6 structure (big-batch LDS staging, transient loads -> no spill) + K-half
// split across blocks for 2x live blocks. Partials to gu0/gu1; silu in quant_h.
__global__ __launch_bounds__(256, 3) void gemm1_kernel(
    const unsigned char* __restrict__ xg,
    const float* __restrict__ xsg,
    const float* __restrict__ wgu,   // [E][2816][2048] fp32 codes
    const float* __restrict__ sgu,   // [E][22][16]
    const int* __restrict__ offs,
    float* __restrict__ gu0,
    float* __restrict__ gu1) {
    int e = blockIdx.z;
    int mt = blockIdx.y;
    int jb = blockIdx.x >> 1;        // 0..43 (32 gate/up col pairs each)
    int kh = blockIdx.x & 1;         // K half
    int o0 = offs[e], o1 = offs[e + 1];
    int ne = o1 - o0;
    int m0 = mt * 128;
    if (m0 >= ne) return;
    int rem = ne - m0;
    int j0 = o0 + m0;

    __shared__ __align__(16) unsigned char Asm[128 * LDA];  // 17408
    __shared__ __align__(16) unsigned char Bsm[64 * LDA];   // 8704
    __shared__ __align__(16) float sxa[128 * 20];           // 10240

    int tid = threadIdx.x;
    {   // stage per-row x scales (2 threads/row)
        int r = tid >> 1, q = tid & 1;
        int j = j0 + r; if (j >= o1) j = o0;
        float4 s0 = *(const float4*)(xsg + j * 16 + q * 8);
        float4 s1 = *(const float4*)(xsg + j * 16 + q * 8 + 4);
        *(float4*)&sxa[r * 20 + q * 8] = s0;
        *(float4*)&sxa[r * 20 + q * 8 + 4] = s1;
    }

    int wave = tid >> 6;
    int lane = tid & 63;
    int lr = lane & 15;
    int lq = lane >> 4;

    // A staging: 4 steps x (8 threads/row, 16B each) — fully coalesced
    int aseg = tid & 7;
    int arow0 = tid >> 3;            // 0..31
    const unsigned char* aBase0;
    const unsigned char* aBase1;
    const unsigned char* aBase2;
    const unsigned char* aBase3;
    {
        int j;
        j = j0 + arow0;       if (j >= o1) j = o0; aBase0 = xg + (long)j * HD + aseg * 16;
        j = j0 + 32 + arow0;  if (j >= o1) j = o0; aBase1 = xg + (long)j * HD + aseg * 16;
        j = j0 + 64 + arow0;  if (j >= o1) j = o0; aBase2 = xg + (long)j * HD + aseg * 16;
        j = j0 + 96 + arow0;  if (j >= o1) j = o0; aBase3 = xg + (long)j * HD + aseg * 16;
    }

    // B staging: coalesced — 32 consecutive lanes cover one row's 512B chunk.
    int bcol = tid & 31;             // float4 (16B) index within 128-float chunk
    int brow0 = tid >> 5;            // 0..7
    const float* bG = wgu + ((long)e * 2816 + jb * 32 + brow0) * HD + bcol * 4;
    const float* bU = wgu + ((long)e * 2816 + 1408 + jb * 32 + brow0) * HD + bcol * 4;
    const float* sgp = sgu + (e * 22 + (jb >> 2)) * 16;
    const float* sup = sgu + (e * 22 + 11 + (jb >> 2)) * 16;

    floatx4 facc[8];
    #pragma unroll
    for (int i = 0; i < 8; i++) facc[i] = fzero4();

    for (int kb = kh * 8; kb < kh * 8 + 8; kb++) {
        // ---- staging phase (all values transient) ----
        {
            uint4 a0 = *(const uint4*)(aBase0 + kb * 128);
            uint4 a1 = *(const uint4*)(aBase1 + kb * 128);
            uint4 a2 = *(const uint4*)(aBase2 + kb * 128);
            uint4 a3 = *(const uint4*)(aBase3 + kb * 128);
            float4 f0 = *(const float4*)(bG + kb * 128);
            float4 f1 = *(const float4*)(bG + kb * 128 + 8 * HD);
            float4 f2 = *(const float4*)(bG + kb * 128 + 16 * HD);
            float4 f3 = *(const float4*)(bG + kb * 128 + 24 * HD);
            float4 f4 = *(const float4*)(bU + kb * 128);
            float4 f5 = *(const float4*)(bU + kb * 128 + 8 * HD);
            float4 f6 = *(const float4*)(bU + kb * 128 + 16 * HD);
            float4 f7 = *(const float4*)(bU + kb * 128 + 24 * HD);
            *(uint4*)(&Asm[(arow0)      * LDA + aseg * 16]) = a0;
            *(uint4*)(&Asm[(arow0 + 32) * LDA + aseg * 16]) = a1;
            *(uint4*)(&Asm[(arow0 + 64) * LDA + aseg * 16]) = a2;
            *(uint4*)(&Asm[(arow0 + 96) * LDA + aseg * 16]) = a3;
            int p0 = __builtin_amdgcn_cvt_pk_fp8_f32(f0.x, f0.y, 0, false);
            p0 = __builtin_amdgcn_cvt_pk_fp8_f32(f0.z, f0.w, p0, true);
            int p1 = __builtin_amdgcn_cvt_pk_fp8_f32(f1.x, f1.y, 0, false);
            p1 = __builtin_amdgcn_cvt_pk_fp8_f32(f1.z, f1.w, p1, true);
            int p2 = __builtin_amdgcn_cvt_pk_fp8_f32(f2.x, f2.y, 0, false);
            p2 = __builtin_amdgcn_cvt_pk_fp8_f32(f2.z, f2.w, p2, true);
            int p3 = __builtin_amdgcn_cvt_pk_fp8_f32(f3.x, f3.y, 0, false);
            p3 = __builtin_amdgcn_cvt_pk_fp8_f32(f3.z, f3.w, p3, true);
            int p4 = __builtin_amdgcn_cvt_pk_fp8_f32(f4.x, f4.y, 0, false);
            p4 = __builtin_amdgcn_cvt_pk_fp8_f32(f4.z, f4.w, p4, true);
            int p5 = __builtin_amdgcn_cvt_pk_fp8_f32(f5.x, f5.y, 0, false);
            p5 = __builtin_amdgcn_cvt_pk_fp8_f32(f5.z, f5.w, p5, true);
            int p6 = __builtin_amdgcn_cvt_pk_fp8_f32(f6.x, f6.y, 0, false);
            p6 = __builtin_amdgcn_cvt_pk_fp8_f32(f6.z, f6.w, p6, true);
            int p7 = __builtin_amdgcn_cvt_pk_fp8_f32(f7.x, f7.y, 0, false);
            p7 = __builtin_amdgcn_cvt_pk_fp8_f32(f7.z, f7.w, p7, true);
            *(unsigned int*)(&Bsm[(brow0)      * LDA + bcol * 4]) = (unsigned int)p0;
            *(unsigned int*)(&Bsm[(brow0 + 8)  * LDA + bcol * 4]) = (unsigned int)p1;
            *(unsigned int*)(&Bsm[(brow0 + 16) * LDA + bcol * 4]) = (unsigned int)p2;
            *(unsigned int*)(&Bsm[(brow0 + 24) * LDA + bcol * 4]) = (unsigned int)p3;
            *(unsigned int*)(&Bsm[(brow0 + 32) * LDA + bcol * 4]) = (unsigned int)p4;
            *(unsigned int*)(&Bsm[(brow0 + 40) * LDA + bcol * 4]) = (unsigned int)p5;
            *(unsigned int*)(&Bsm[(brow0 + 48) * LDA + bcol * 4]) = (unsigned int)p6;
            *(unsigned int*)(&Bsm[(brow0 + 56) * LDA + bcol * 4]) = (unsigned int)p7;
        }
        __syncthreads();
        // ---- MFMA phase ----
        floatx4 cacc[8];
        #pragma unroll
        for (int i = 0; i < 8; i++) cacc[i] = fzero4();
        #pragma unroll
        for (int ks = 0; ks < 4; ks++) {
            long a[2], b[4];
            #pragma unroll
            for (int mi = 0; mi < 2; mi++)
                a[mi] = *(const long*)(&Asm[(wave * 32 + mi * 16 + lr) * LDA + ks * 32 + lq * 8]);
            #pragma unroll
            for (int ni = 0; ni < 4; ni++)
                b[ni] = *(const long*)(&Bsm[(ni * 16 + lr) * LDA + ks * 32 + lq * 8]);
            #pragma unroll
            for (int mi = 0; mi < 2; mi++)
                #pragma unroll
                for (int ni = 0; ni < 4; ni++)
                    cacc[mi * 4 + ni] = __builtin_amdgcn_mfma_f32_16x16x32_fp8_fp8(
                        a[mi], b[ni], cacc[mi * 4 + ni], 0, 0, 0);
        }
        float sg = sgp[kb];
        float su = sup[kb];
        #pragma unroll
        for (int mi = 0; mi < 2; mi++) {
            #pragma unroll
            for (int reg = 0; reg < 4; reg++) {
                float sx = sxa[(wave * 32 + mi * 16 + lq * 4 + reg) * 20 + kb];
                #pragma unroll
                for (int ni = 0; ni < 4; ni++) {
                    float sw = (ni < 2) ? sg : su;
                    facc[mi * 4 + ni][reg] += cacc[mi * 4 + ni][reg] * (sw * sx);
                }
            }
        }
        __syncthreads();
    }

    // epilogue: store gate/up fp32 partials (silu happens in quant_h)
    float* gu = kh ? gu1 : gu0;
    #pragma unroll
    for (int mi = 0; mi < 2; mi++) {
        #pragma unroll
        for (int ni = 0; ni < 4; ni++) {
            #pragma unroll
            for (int reg = 0; reg < 4; reg++) {
                int r = wave * 32 + mi * 16 + lq * 4 + reg;
                if (r < rem) {
                    long base = (long)(j0 + r) * 2816;
                    long col = (ni < 2) ? (jb * 32 + ni * 16 + lr)
                                        : (1408 + jb * 32 + (ni - 2) * 16 + lr);
                    gu[base + col] = facc[mi * 4 + ni][reg];
                }
            }
        }
    }
}

// ---------------- gemm2: BM=128 x BN=32 H-cols, K-split-2, atomic scatter ----
__global__ __launch_bounds__(256, 4) void gemm2_kernel(
    const unsigned char* __restrict__ hq,
    const float* __restrict__ hs,
    const float* __restrict__ wd,    // [E][2048][1408] fp32 codes
    const float* __restrict__ sd,    // [E][16][11]
    const int* __restrict__ offs,
    const int* __restrict__ tok,
    const float* __restrict__ wgt,
    float* __restrict__ out) {
    int e = blockIdx.z;
    int mt = blockIdx.y;
    int jb = blockIdx.x >> 1;        // 0..63 (32 H-cols each)
    int kh = blockIdx.x & 1;
    int o0 = offs[e], o1 = offs[e + 1];
    int ne = o1 - o0;
    int m0 = mt * 128;
    if (m0 >= ne) return;
    int rem = ne - m0;
    int j0 = o0 + m0;

    __shared__ __align__(16) unsigned char Asm[128 * LDA];  // 17408
    __shared__ __align__(16) unsigned char Bsm[32 * LDA];   // 4352
    __shared__ __align__(16) float sha[128 * 12];           // 6144
    __shared__ int tokL[128];
    __shared__ float wgtL[128];

    int tid = threadIdx.x;
    if (tid < 128) {
        int j = j0 + tid;
        int valid = j < o1;
        if (!valid) j = o0;
        tokL[tid] = tok[j];
        wgtL[tid] = valid ? wgt[j] : 0.0f;
        const float* s = hs + j * 11;
        #pragma unroll
        for (int k = 0; k < 11; k++) sha[tid * 12 + k] = s[k];
    }

    int wave = tid >> 6;
    int lane = tid & 63;
    int lr = lane & 15;
    int lq = lane >> 4;

    int aseg = tid & 7;
    int arow0 = tid >> 3;            // 0..31
    const unsigned char* aBase0;
    const unsigned char* aBase1;
    const unsigned char* aBase2;
    const unsigned char* aBase3;
    {
        int j;
        j = j0 + arow0;       if (j >= o1) j = o0; aBase0 = hq + (long)j * ID + aseg * 16;
        j = j0 + 32 + arow0;  if (j >= o1) j = o0; aBase1 = hq + (long)j * ID + aseg * 16;
        j = j0 + 64 + arow0;  if (j >= o1) j = o0; aBase2 = hq + (long)j * ID + aseg * 16;
        j = j0 + 96 + arow0;  if (j >= o1) j = o0; aBase3 = hq + (long)j * ID + aseg * 16;
    }

    // B staging: coalesced — 32 lanes cover one row's 512B chunk
    int bcol = tid & 31;
    int brow0 = tid >> 5;            // 0..7
    const float* bB = wd + ((long)e * HD + jb * 32 + brow0) * ID + bcol * 4;
    const float* sdp = sd + (e * 16 + (jb >> 2)) * 11;

    floatx4 facc[4];
    #pragma unroll
    for (int i = 0; i < 4; i++) facc[i] = fzero4();

    int kb0 = kh ? 6 : 0, kb1 = kh ? 11 : 6;
    for (int kb = kb0; kb < kb1; kb++) {
        {
            uint4 a0 = *(const uint4*)(aBase0 + kb * 128);
            uint4 a1 = *(const uint4*)(aBase1 + kb * 128);
            uint4 a2 = *(const uint4*)(aBase2 + kb * 128);
            uint4 a3 = *(const uint4*)(aBase3 + kb * 128);
            float4 f0 = *(const float4*)(bB + kb * 128);
            float4 f1 = *(const float4*)(bB + kb * 128 + 8 * ID);
            float4 f2 = *(const float4*)(bB + kb * 128 + 16 * ID);
            float4 f3 = *(const float4*)(bB + kb * 128 + 24 * ID);
            *(uint4*)(&Asm[(arow0)      * LDA + aseg * 16]) = a0;
            *(uint4*)(&Asm[(arow0 + 32) * LDA + aseg * 16]) = a1;
            *(uint4*)(&Asm[(arow0 + 64) * LDA + aseg * 16]) = a2;
            *(uint4*)(&Asm[(arow0 + 96) * LDA + aseg * 16]) = a3;
            int p0 = __builtin_amdgcn_cvt_pk_fp8_f32(f0.x, f0.y, 0, false);
            p0 = __builtin_amdgcn_cvt_pk_fp8_f32(f0.z, f0.w, p0, true);
            int p1 = __builtin_amdgcn_cvt_pk_fp8_f32(f1.x, f1.y, 0, false);
            p1 = __builtin_amdgcn_cvt_pk_fp8_f32(f1.z, f1.w, p1, true);
            int p2 = __builtin_amdgcn_cvt_pk_fp8_f32(f2.x, f2.y, 0, false);
            p2 = __builtin_amdgcn_cvt_pk_fp8_f32(f2.z, f2.w, p2, true);
            int p3 = __builtin_amdgcn_cvt_pk_fp8_f32(f3.x, f3.y, 0, false);
            p3 = __builtin_amdgcn_cvt_pk_fp8_f32(f3.z, f3.w, p3, true);
            *(unsigned int*)(&Bsm[(brow0)      * LDA + bcol * 4]) = (unsigned int)p0;
            *(unsigned int*)(&Bsm[(brow0 + 8)  * LDA + bcol * 4]) = (unsigned int)p1;
            *(unsigned int*)(&Bsm[(brow0 + 16) * LDA + bcol * 4]) = (unsigned int)p2;
            *(unsigned int*)(&Bsm[(brow0 + 24) * LDA + bcol * 4]) = (unsigned int)p3;
        }
        __syncthreads();
        floatx4 cacc[4];
        #pragma unroll
        for (int i = 0; i < 4; i++) cacc[i] = fzero4();
        #pragma unroll
        for (int ks = 0; ks < 4; ks++) {
            long a[2], b[2];
            #pragma unroll
            for (int mi = 0; mi < 2; mi++)
                a[mi] = *(const long*)(&Asm[(wave * 32 + mi * 16 + lr) * LDA + ks * 32 + lq * 8]);
            #pragma unroll
            for (int ni = 0; ni < 2; ni++)
                b[ni] = *(const long*)(&Bsm[(ni * 16 + lr) * LDA + ks * 32 + lq * 8]);
            #pragma unroll
            for (int mi = 0; mi < 2; mi++)
                #pragma unroll
                for (int ni = 0; ni < 2; ni++)
                    cacc[mi * 2 + ni] = __builtin_amdgcn_mfma_f32_16x16x32_fp8_fp8(
                        a[mi], b[ni], cacc[mi * 2 + ni], 0, 0, 0);
        }
        float sw = sdp[kb];
        #pragma unroll
        for (int mi = 0; mi < 2; mi++) {
            #pragma unroll
            for (int reg = 0; reg < 4; reg++) {
                float sh = sha[(wave * 32 + mi * 16 + lq * 4 + reg) * 12 + kb];
                #pragma unroll
                for (int ni = 0; ni < 2; ni++)
                    facc[mi * 2 + ni][reg] += cacc[mi * 2 + ni][reg] * (sw * sh);
            }
        }
        __syncthreads();
    }

    #pragma unroll
    for (int mi = 0; mi < 2; mi++) {
        #pragma unroll
        for (int ni = 0; ni < 2; ni++) {
            #pragma unroll
            for (int reg = 0; reg < 4; reg++) {
                int r = wave * 32 + mi * 16 + lq * 4 + reg;
                if (r < rem) {
                    float v = facc[mi * 2 + ni][reg] * wgtL[r];
                    atomicAdd(out + (long)tokL[r] * HD + jb * 32 + ni * 16 + lr, v);
                }
            }
        }
    }
}

extern "C" void kernel_launch(void* const* d_in, const int* in_sizes, int n_in,
                              void* d_out, int out_size, void* d_ws, size_t ws_size,
                              hipStream_t stream) {
    (void)in_sizes; (void)n_in; (void)out_size; (void)ws_size;
    const float* x   = (const float*)d_in[0];
    const int*   tki = (const int*)d_in[1];
    const float* tkw = (const float*)d_in[2];
    const float* wgu = (const float*)d_in[3];
    const float* sgu = (const float*)d_in[4];
    const float* wd  = (const float*)d_in[5];
    const float* sd  = (const float*)d_in[6];
    float* out = (float*)d_out;
    char* ws = (char*)d_ws;

    int*   offs = (int*)(ws + OFF_OFFS);
    int*   tok  = (int*)(ws + OFF_TOK);
    float* wgt  = (float*)(ws + OFF_WGT);
    int*   ent  = (int*)(ws + OFF_ENT);
    float* xsg  = (float*)(ws + OFF_XSG);
    unsigned char* xg = (unsigned char*)(ws + OFF_XG);
    float* hs   = (float*)(ws + OFF_HS);
    unsigned char* hq = (unsigned char*)(ws + OFF_HQ);
    float* gu0  = (float*)(ws + OFF_GU0);
    float* gu1  = (float*)(ws + OFF_GU1);

    hipMemsetAsync(d_out, 0, (size_t)NT * HD * sizeof(float), stream);
    route_kernel<<<1, 1024, 0, stream>>>(tki, tkw, offs, tok, wgt, ent);
    quant_x_kernel<<<2048, 256, 0, stream>>>(x, ent, xg, xsg);
    gemm1_kernel<<<dim3(88, 8, NE), 256, 0, stream>>>(xg, xsg, wgu, sgu, offs, gu0, gu1);
    quant_h_kernel<<<2816, 256, 0, stream>>>(gu0, gu1, hq, hs);
    gemm2_kernel<<<dim3(128, 8, NE), 256, 0, stream>>>(hq, hs, wd, sd, offs, tok, wgt, out);
}